// Round 6
// baseline (643.050 us; speedup 1.0000x reference)
//
#include <hip/hip_runtime.h>
#include <math.h>

#define KD     768     // embedding dim (elements = bytes in fp8)
#define MT     128     // M tile (queries)
#define NT     128     // N tile (bank rows)
#define KB     128     // K elements per chunk (one mfma_scale K=128)
#define NSPLIT 16      // bank splits per M tile
#define BIGF   3.0e38f

typedef __attribute__((ext_vector_type(4))) int   i32x4;
typedef __attribute__((ext_vector_type(8))) int   i32x8;
typedef __attribute__((ext_vector_type(4))) float f32x4;

// ---- software RNE float -> OCP e4m3fn (data ~N(0,1); saturation irrelevant)
__device__ __forceinline__ unsigned f2e4m3(float x) {
    unsigned u = __float_as_uint(x);
    unsigned s = (u >> 24) & 0x80u;
    float ax = __uint_as_float(u & 0x7fffffffu);
    if (ax < 0.015625f) {                       // subnormal region: step 2^-9
        int n = (int)rintf(ax * 512.0f);        // RNE, n in [0,8]
        if (n >= 8) return s | 0x08u;
        return s | (unsigned)n;
    }
    if (ax >= 464.0f) return s | 0x7Eu;         // saturate to 448
    unsigned m = __float_as_uint(ax);
    unsigned low = m & 0xFFFFFu;
    unsigned r = m >> 20;
    r += (low > 0x80000u) || (low == 0x80000u && (r & 1u));
    int ef = (int)(r >> 3) - 120;               // -127 + 7 (carry-safe)
    return s | ((unsigned)ef << 3) | (r & 7u);
}

__device__ __forceinline__ void ins3(float* t, float v) {
    float lo0 = fminf(t[0], v);
    float hi0 = fmaxf(t[0], v);
    float lo1 = fminf(t[1], hi0);
    float hi1 = fmaxf(t[1], hi0);
    float lo2 = fminf(t[2], hi1);
    t[0] = lo0; t[1] = lo1; t[2] = lo2;
}
__device__ __forceinline__ void async16(unsigned char* lds, const unsigned char* g) {
    __builtin_amdgcn_global_load_lds(
        (const __attribute__((address_space(1))) unsigned int*)g,
        (__attribute__((address_space(3))) unsigned int*)lds, 16, 0, 0);
}

// ---- emb [B][768][1024] -> qf8 [B*1024][768] e4m3 (LDS tile transpose) ----
__global__ void q_prep_k(const float* __restrict__ emb, unsigned char* __restrict__ qf8) {
    __shared__ float s[64][65];
    int b   = blockIdx.x >> 4;
    int hw0 = (blockIdx.x & 15) * 64;
    const float* src = emb + (size_t)b * KD * 1024;
    unsigned int* q4 = (unsigned int*)qf8;
    for (int e0 = 0; e0 < KD; e0 += 64) {
        __syncthreads();
        #pragma unroll
        for (int i = 0; i < 16; ++i) {
            int idx = threadIdx.x + i * 256;      // 0..4095
            int ee = idx >> 6, hh = idx & 63;
            s[ee][hh] = src[(size_t)(e0 + ee) * 1024 + hw0 + hh];
        }
        __syncthreads();
        #pragma unroll
        for (int i = 0; i < 4; ++i) {
            int slot = threadIdx.x + i * 256;     // 0..1023 : (qq, e4)
            int qq = slot >> 4, e4 = slot & 15;
            unsigned p = f2e4m3(s[e4 * 4 + 0][qq])
                       | (f2e4m3(s[e4 * 4 + 1][qq]) << 8)
                       | (f2e4m3(s[e4 * 4 + 2][qq]) << 16)
                       | (f2e4m3(s[e4 * 4 + 3][qq]) << 24);
            q4[((size_t)b * 1024 + hw0 + qq) * (KD / 4) + e0 / 4 + e4] = p;
        }
    }
}

// ---- bank -> bf8 e4m3 (zero-padded) + exact fp32 b2 norms (BIGF pad) ----
__global__ void bank_prep_k(const float* __restrict__ bank, unsigned char* __restrict__ bf8,
                            float* __restrict__ b2, int N, int Npad) {
    int gid = blockIdx.x * 256 + threadIdx.x;
    int row = gid >> 6, lane = gid & 63;
    if (row >= Npad) return;
    unsigned int* b4 = (unsigned int*)bf8;
    if (row < N) {
        const float4* src = (const float4*)(bank + (size_t)row * KD);
        float s = 0.f;
        #pragma unroll
        for (int i = 0; i < KD / 256; ++i) {      // 3 iters of float4
            float4 v = src[lane + i * 64];
            s = fmaf(v.x, v.x, s); s = fmaf(v.y, v.y, s);
            s = fmaf(v.z, v.z, s); s = fmaf(v.w, v.w, s);
            unsigned p = f2e4m3(v.x) | (f2e4m3(v.y) << 8)
                       | (f2e4m3(v.z) << 16) | (f2e4m3(v.w) << 24);
            b4[(size_t)row * (KD / 4) + lane + i * 64] = p;
        }
        #pragma unroll
        for (int off = 32; off; off >>= 1) s += __shfl_down(s, off, 64);
        if (lane == 0) b2[row] = s;
    } else {
        #pragma unroll
        for (int i = 0; i < KD / 256; ++i) b4[(size_t)row * (KD / 4) + lane + i * 64] = 0;
        if (lane == 0) b2[row] = BIGF;
    }
}

// ---- exact fp32 q norms: one thread per query (coalesced over hw) ----
__global__ void q_norms_k(const float* __restrict__ emb, float* __restrict__ q2, int Q) {
    int idx = blockIdx.x * blockDim.x + threadIdx.x;
    if (idx >= Q) return;
    int b  = idx >> 10;
    int hw = idx & 1023;
    const float* p = emb + (size_t)b * KD * 1024 + hw;
    float s = 0.f;
    #pragma unroll 8
    for (int e = 0; e < KD; e++) { float v = p[(size_t)e << 10]; s = fmaf(v, v, s); }
    q2[idx] = s;
}

__device__ __forceinline__ void stage_chunk(unsigned char (*stage)[MT * KB],
                                            const unsigned char* gA, const unsigned char* gB,
                                            int k0, int tid) {
    // 1024 slots of 16B per operand; slot s=(m,g) holds k-group g^(m&7) (XOR swizzle)
    #pragma unroll
    for (int i = 0; i < 4; ++i) {
        int s = tid + i * 256;
        int m = s >> 3, g = s & 7;
        int G = g ^ (m & 7);
        async16(&stage[0][s * 16], gA + (size_t)m * KD + k0 + G * 16);
    }
    #pragma unroll
    for (int i = 0; i < 4; ++i) {
        int s = tid + i * 256;
        int m = s >> 3, g = s & 7;
        int G = g ^ (m & 7);
        async16(&stage[1][s * 16], gB + (size_t)m * KD + k0 + G * 16);
    }
}

__device__ __forceinline__ i32x8 frag_read(const unsigned char* st, int row_base,
                                           int c0, int c1) {
    i32x4 lo = *(const i32x4*)&st[row_base + c0];
    i32x4 hi = *(const i32x4*)&st[row_base + c1];
    return __builtin_shufflevector(lo, hi, 0, 1, 2, 3, 4, 5, 6, 7);
}

__device__ __forceinline__ void mfma_chunk(const unsigned char (*stage)[MT * KB],
                                           f32x4 acc[4][4], int wm, int wn,
                                           int l15, int quad, int xr) {
    // lane needs k = quad*32..+31 -> 16B groups 2q, 2q+1, XOR-swizzled by xr
    const int c0 = ((2 * quad) ^ xr) * 16;
    const int c1 = ((2 * quad + 1) ^ xr) * 16;
    i32x8 bfr[4];
    #pragma unroll
    for (int ni = 0; ni < 4; ++ni)
        bfr[ni] = frag_read(stage[1], (64 * wn + 16 * ni + l15) * KB, c0, c1);
    #pragma unroll
    for (int mi = 0; mi < 4; ++mi) {
        i32x8 af = frag_read(stage[0], (64 * wm + 16 * mi + l15) * KB, c0, c1);
        #pragma unroll
        for (int ni = 0; ni < 4; ++ni)
            acc[mi][ni] = __builtin_amdgcn_mfma_scale_f32_16x16x128_f8f6f4(
                af, bfr[ni], acc[mi][ni], 0, 0,   // cbsz=fp8, blgp=fp8
                0, 127, 0, 127);                  // identity E8M0 scales (2^0)
    }
}

// epilogue: s = b2 - 2*dot (q2 added later; per-row constant preserves order)
__device__ __forceinline__ void do_epilogue(const f32x4 acc[4][4], const float b2v[4],
                                            float* top3) {
    #pragma unroll
    for (int ni = 0; ni < 4; ++ni)
        #pragma unroll
        for (int mi = 0; mi < 4; ++mi)
            #pragma unroll
            for (int r = 0; r < 4; ++r) {
                float s = fmaf(-2.0f, acc[mi][ni][r], b2v[ni]);
                ins3(&top3[(mi * 4 + r) * 3], s);
            }
}

// ---- main: fp8 (identity-scale) K=128 MFMA distance GEMM + fused top-3 ----
__global__ __launch_bounds__(256, 4)
void knn_mfma_k(const unsigned char* __restrict__ qf8, const unsigned char* __restrict__ bf8,
                const float* __restrict__ b2g, float* __restrict__ cand,
                int ntiles, int Q) {
    __shared__ unsigned char stage[2][MT * KB];   // A tile | B tile (32768 B)

    const int tid  = threadIdx.x;
    const int lane = tid & 63;
    const int quad = lane >> 4;
    const int l15  = lane & 15;
    const int wid  = tid >> 6;
    const int wm   = wid & 1;
    const int wn   = wid >> 1;

    const int bx   = blockIdx.x;
    const int xcd  = bx & 7;
    const int j    = bx >> 3;                  // 0..127
    const int sp   = (j >> 4) + 8 * (xcd >> 2);
    const int mt   = (xcd & 3) * 16 + (j & 15);
    const int Mbase = mt * MT;

    float top3[48];
    #pragma unroll
    for (int i = 0; i < 48; ++i) top3[i] = BIGF;

    const int xr = l15 & 7;
    const unsigned char* gA = qf8 + (size_t)Mbase * KD;

    f32x4 acc[4][4];
    float b2v[4];
    bool first = true;

    for (int nt = sp; nt < ntiles; nt += NSPLIT) {
        const size_t nbase = (size_t)nt * NT;
        const unsigned char* gB = bf8 + nbase * KD;

        __syncthreads();                       // prior chunk reads complete
        stage_chunk(stage, gA, gB, 0, tid);    // kc0 staging in flight
        float t0 = b2g[nbase + 64 * wn + 0  + l15];
        float t1 = b2g[nbase + 64 * wn + 16 + l15];
        float t2 = b2g[nbase + 64 * wn + 32 + l15];
        float t3 = b2g[nbase + 64 * wn + 48 + l15];
        if (!first) do_epilogue(acc, b2v, top3);   // overlaps staging latency
        first = false;
        b2v[0] = t0; b2v[1] = t1; b2v[2] = t2; b2v[3] = t3;
        #pragma unroll
        for (int a = 0; a < 4; ++a)
            #pragma unroll
            for (int b = 0; b < 4; ++b) acc[a][b] = (f32x4){0.f, 0.f, 0.f, 0.f};
        __syncthreads();                       // kc0 loads complete
        mfma_chunk(stage, acc, wm, wn, l15, quad, xr);

        for (int kc = 1; kc < KD / KB; ++kc) {
            __syncthreads();
            stage_chunk(stage, gA, gB, kc * KB, tid);
            __syncthreads();
            mfma_chunk(stage, acc, wm, wn, l15, quad, xr);
        }
    }
    do_epilogue(acc, b2v, top3);

    // merge the 16 column-partials per query row via shfl_xor butterfly
    #pragma unroll
    for (int mi = 0; mi < 4; ++mi)
        #pragma unroll
        for (int r = 0; r < 4; ++r) {
            float a0 = top3[(mi * 4 + r) * 3 + 0];
            float a1 = top3[(mi * 4 + r) * 3 + 1];
            float a2 = top3[(mi * 4 + r) * 3 + 2];
            #pragma unroll
            for (int off = 1; off < 16; off <<= 1) {
                float b0 = __shfl_xor(a0, off, 64);
                float b1 = __shfl_xor(a1, off, 64);
                float b2x = __shfl_xor(a2, off, 64);
                float t[3] = {a0, a1, a2};
                ins3(t, b0); ins3(t, b1); ins3(t, b2x);
                a0 = t[0]; a1 = t[1]; a2 = t[2];
            }
            if (l15 == 0) {
                int row = Mbase + 64 * wm + 16 * mi + 4 * quad + r;
                float* o = cand + ((size_t)(sp * 2 + wn) * Q + row) * 3;
                o[0] = a0; o[1] = a1; o[2] = a2;
            }
        }
}

// ---- merge 32 split-partials (s = b2-2dot) -> d2 = q2+s -> mean sqrt ----
__global__ void scores_k(const float* __restrict__ cand, const float* __restrict__ q2g,
                         float* __restrict__ scores, int Q) {
    int idx = blockIdx.x * blockDim.x + threadIdx.x;
    if (idx >= Q) return;
    float best[3] = {BIGF, BIGF, BIGF};
    for (int sp = 0; sp < NSPLIT * 2; sp++) {
        const float* c = cand + ((size_t)sp * Q + idx) * 3;
        ins3(best, c[0]); ins3(best, c[1]); ins3(best, c[2]);
    }
    float q2 = q2g[idx];
    float s = (sqrtf(fmaxf(q2 + best[0], 1e-12f)) +
               sqrtf(fmaxf(q2 + best[1], 1e-12f)) +
               sqrtf(fmaxf(q2 + best[2], 1e-12f))) * (1.f / 3.f);
    scores[idx] = s;
}

// ---- bilinear x16 upsample, half-pixel, edge clamp ----
__global__ void upsample_k(const float* __restrict__ scores, float* __restrict__ out, int total) {
    int idx = blockIdx.x * blockDim.x + threadIdx.x;
    if (idx >= total) return;
    int x = idx & 511;
    int y = (idx >> 9) & 511;
    int b = idx >> 18;
    float sx = (x + 0.5f) * (1.f / 16.f) - 0.5f;
    float sy = (y + 0.5f) * (1.f / 16.f) - 0.5f;
    int x0 = (int)floorf(sx);
    int y0 = (int)floorf(sy);
    float wx = sx - (float)x0;
    float wy = sy - (float)y0;
    int x0c = min(max(x0, 0), 31), x1c = min(max(x0 + 1, 0), 31);
    int y0c = min(max(y0, 0), 31), y1c = min(max(y0 + 1, 0), 31);
    const float* sb = scores + (size_t)b * 1024;
    float v00 = sb[y0c * 32 + x0c], v01 = sb[y0c * 32 + x1c];
    float v10 = sb[y1c * 32 + x0c], v11 = sb[y1c * 32 + x1c];
    float v0 = v00 + wx * (v01 - v00);
    float v1 = v10 + wx * (v11 - v10);
    out[idx] = v0 + wy * (v1 - v0);
}

extern "C" void kernel_launch(void* const* d_in, const int* in_sizes, int n_in,
                              void* d_out, int out_size, void* d_ws, size_t ws_size,
                              hipStream_t stream) {
    const float* emb  = (const float*)d_in[0];
    const float* bank = (const float*)d_in[1];
    const int Q      = in_sizes[0] / KD;             // 8192
    const int B      = Q / 1024;                     // 8
    const int Nbank  = in_sizes[1] / KD;             // 20000
    const int ntiles = (Nbank + NT - 1) / NT;        // 157
    const int Npad   = ntiles * NT;                  // 20096
    const int Mtiles = Q / MT;                       // 64

    // workspace layout
    unsigned char* qf8 = (unsigned char*)d_ws;                         // Q*KD bytes
    unsigned char* bf8 = qf8 + (size_t)Q * KD;                         // Npad*KD bytes
    float* fbase  = (float*)(bf8 + (size_t)Npad * KD);
    float* q2     = fbase;                                             // Q
    float* b2     = q2 + Q;                                            // Npad
    float* cand   = b2 + Npad;                                         // NSPLIT*2*Q*3
    float* scores = cand + (size_t)NSPLIT * 2 * Q * 3;                 // Q
    float* out    = (float*)d_out;

    hipLaunchKernelGGL(q_prep_k, dim3(B * 16), dim3(256), 0, stream, emb, qf8);
    hipLaunchKernelGGL(bank_prep_k, dim3((Npad * 64 + 255) / 256), dim3(256), 0, stream,
                       bank, bf8, b2, Nbank, Npad);
    hipLaunchKernelGGL(q_norms_k, dim3((Q + 255) / 256), dim3(256), 0, stream, emb, q2, Q);
    hipLaunchKernelGGL(knn_mfma_k, dim3(Mtiles * NSPLIT), dim3(256), 0, stream,
                       qf8, bf8, b2, cand, ntiles, Q);
    hipLaunchKernelGGL(scores_k, dim3((Q + 255) / 256), dim3(256), 0, stream,
                       cand, q2, scores, Q);
    hipLaunchKernelGGL(upsample_k, dim3((out_size + 255) / 256), dim3(256), 0, stream,
                       scores, out, out_size);
}